// Round 4
// baseline (945.503 us; speedup 1.0000x reference)
//
#include <hip/hip_runtime.h>

#define DIM 128

// h[r][o] = sum_i x[r][i] * W[o][i]
// Each thread owns output column o and holds W row o in 32 float4 registers.
// x row address is wave-uniform (readfirstlane) -> scalar-load path, broadcast.
__global__ __launch_bounds__(256, 2) void gemm_xwt(
    const float* __restrict__ x, const float* __restrict__ W,
    float* __restrict__ h, int N)
{
    const int o = threadIdx.x & (DIM - 1);
    const int g = threadIdx.x >> 7;  // 0 or 1: two row-slots per block

    float4 w[32];
    const float4* Wrow = reinterpret_cast<const float4*>(W + o * DIM);
#pragma unroll
    for (int i = 0; i < 32; ++i) w[i] = Wrow[i];

    const int stride = gridDim.x * 2;
    for (int r = blockIdx.x * 2 + g; r < N; r += stride) {
        const int ru = __builtin_amdgcn_readfirstlane(r);
        const float4* xr = reinterpret_cast<const float4*>(x + (size_t)ru * DIM);
        float acc = 0.f;
#pragma unroll
        for (int i = 0; i < 32; ++i) {
            float4 xv = xr[i];
            acc = fmaf(w[i].x, xv.x, acc);
            acc = fmaf(w[i].y, xv.y, acc);
            acc = fmaf(w[i].z, xv.z, acc);
            acc = fmaf(w[i].w, xv.w, acc);
        }
        h[(size_t)ru * DIM + o] = acc;
    }
}

// out[dst][c] += h[src][c] for each edge. 128 threads per edge, 2 edges per
// 256-thread block per iteration. Row accesses are 512B contiguous.
__global__ __launch_bounds__(256) void scatter_add(
    const float* __restrict__ h, const int* __restrict__ ei,
    float* __restrict__ out, int E)
{
    const int c = threadIdx.x & (DIM - 1);
    const int slot = threadIdx.x >> 7;
    const int slotsPerIter = gridDim.x * 2;
    for (int e = blockIdx.x * 2 + slot; e < E; e += slotsPerIter) {
        const int s = ei[e];
        const int d = ei[E + e];
        const float v = h[(size_t)s * DIM + c];
        atomicAdd(out + (size_t)d * DIM + c, v);
    }
}

extern "C" void kernel_launch(void* const* d_in, const int* in_sizes, int n_in,
                              void* d_out, int out_size, void* d_ws, size_t ws_size,
                              hipStream_t stream) {
    const float* x  = (const float*)d_in[0];
    const float* W  = (const float*)d_in[1];
    const int*   ei = (const int*)d_in[2];   // harness delivers integer inputs as int32
    float* out = (float*)d_out;

    const int N = in_sizes[0] / DIM;   // 100000
    const int E = in_sizes[2] / 2;     // 1600000

    float* h = (float*)d_ws;           // N*DIM floats = 51.2 MB scratch

    // d_out is poisoned 0xAA before every timed launch -> zero it (accumulator).
    hipMemsetAsync(d_out, 0, (size_t)out_size * sizeof(float), stream);

    gemm_xwt<<<1024, 256, 0, stream>>>(x, W, h, N);
    scatter_add<<<4096, 256, 0, stream>>>(h, ei, out, E);
}

// Round 5
// 428.709 us; speedup vs baseline: 2.2055x; 2.2055x over previous
//
#include <hip/hip_runtime.h>

typedef float f32x4 __attribute__((ext_vector_type(4)));
typedef short s16x8 __attribute__((ext_vector_type(8)));

#define DIM 128
#define BM  128   // rows per gemm block

static __device__ __forceinline__ unsigned short f2bf(float f) {
    union { float f; unsigned u; } v; v.f = f;
    unsigned r = v.u + 0x7fff + ((v.u >> 16) & 1);  // RNE
    return (unsigned short)(r >> 16);
}

// h_bf16[r][o] = bf16( sum_k x[r][k] * W[o][k] )  via 16x16x32 bf16 MFMA.
// A = x tile [128][128], B^T = W [128][128], both staged (fp32->bf16) into
// padded LDS (+8 bf16/row => row stride 272B => 2-way-max bank aliasing).
__global__ __launch_bounds__(256) void gemm_mfma(
    const float* __restrict__ x, const float* __restrict__ W,
    unsigned short* __restrict__ h, int N)
{
    __shared__ unsigned short xs[BM][DIM + 8];
    __shared__ unsigned short wsh[DIM][DIM + 8];
    const int tid = threadIdx.x;
    const int base = blockIdx.x * BM;

    // stage W (every block; W is 64KB fp32, L2/L3-resident)
    for (int u = tid; u < DIM * 16; u += 256) {
        const int row = u >> 4, ch = u & 15;
        const float* p = W + row * DIM + ch * 8;
        unsigned short t[8];
#pragma unroll
        for (int j = 0; j < 8; ++j) t[j] = f2bf(p[j]);
        *reinterpret_cast<s16x8*>(&wsh[row][ch * 8]) = *reinterpret_cast<const s16x8*>(t);
    }
    // stage x tile
    for (int u = tid; u < BM * 16; u += 256) {
        const int row = u >> 4, ch = u & 15;
        const int grow = base + row;
        unsigned short t[8];
        if (grow < N) {
            const float* p = x + (size_t)grow * DIM + ch * 8;
#pragma unroll
            for (int j = 0; j < 8; ++j) t[j] = f2bf(p[j]);
        } else {
#pragma unroll
            for (int j = 0; j < 8; ++j) t[j] = 0;
        }
        *reinterpret_cast<s16x8*>(&xs[row][ch * 8]) = *reinterpret_cast<const s16x8*>(t);
    }
    __syncthreads();

    const int wv = tid >> 6;   // wave 0..3 -> rows wv*32..wv*32+31
    const int l  = tid & 63;
    const int lr = l & 15;     // frag row/col
    const int lk = l >> 4;     // k-block (8 bf16 each)

    f32x4 acc[2][8];
#pragma unroll
    for (int i = 0; i < 2; ++i)
#pragma unroll
        for (int j = 0; j < 8; ++j) acc[i][j] = (f32x4)(0.f);

#pragma unroll
    for (int ks = 0; ks < 4; ++ks) {
        s16x8 a[2], b[8];
#pragma unroll
        for (int rf = 0; rf < 2; ++rf)
            a[rf] = *reinterpret_cast<const s16x8*>(&xs[wv * 32 + rf * 16 + lr][ks * 32 + lk * 8]);
#pragma unroll
        for (int cf = 0; cf < 8; ++cf)
            b[cf] = *reinterpret_cast<const s16x8*>(&wsh[cf * 16 + lr][ks * 32 + lk * 8]);
#pragma unroll
        for (int rf = 0; rf < 2; ++rf)
#pragma unroll
            for (int cf = 0; cf < 8; ++cf)
                acc[rf][cf] = __builtin_amdgcn_mfma_f32_16x16x32_bf16(a[rf], b[cf], acc[rf][cf], 0, 0, 0);
    }

    // D mapping (m89-verified): col = l&15, row = (l>>4)*4 + r
#pragma unroll
    for (int rf = 0; rf < 2; ++rf)
#pragma unroll
        for (int r = 0; r < 4; ++r) {
            const int grow = base + wv * 32 + rf * 16 + lk * 4 + r;
            if (grow < N) {
#pragma unroll
                for (int cf = 0; cf < 8; ++cf)
                    h[(size_t)grow * DIM + cf * 16 + lr] = f2bf(acc[rf][cf][r]);
            }
        }
}

// dst histogram (int atomics, L2-resident counters)
__global__ void hist(const int* __restrict__ ei, int* __restrict__ cnt, int E) {
    int i = blockIdx.x * blockDim.x + threadIdx.x;
    const int stride = gridDim.x * blockDim.x;
    for (int e = i; e < E; e += stride) atomicAdd(&cnt[ei[E + e]], 1);
}

// per-256-block exclusive scan + block sums (Hillis-Steele)
__global__ __launch_bounds__(256) void scan1(const int* __restrict__ cnt, int* __restrict__ exc,
                                             int* __restrict__ bsum, int N) {
    __shared__ int s[256];
    const int t = threadIdx.x;
    const int i = blockIdx.x * 256 + t;
    const int v = (i < N) ? cnt[i] : 0;
    s[t] = v;
    __syncthreads();
    int val = v;
#pragma unroll
    for (int d = 1; d < 256; d <<= 1) {
        const int add = (t >= d) ? s[t - d] : 0;
        __syncthreads();
        val += add;
        s[t] = val;
        __syncthreads();
    }
    if (i < N) exc[i] = val - v;
    if (t == 255) bsum[blockIdx.x] = val;
}

// single-block exclusive scan of block sums (nb <= 512)
__global__ __launch_bounds__(512) void scan2(int* __restrict__ bsum, int nb) {
    __shared__ int s[512];
    const int t = threadIdx.x;
    const int v = (t < nb) ? bsum[t] : 0;
    s[t] = v;
    __syncthreads();
    int val = v;
#pragma unroll
    for (int d = 1; d < 512; d <<= 1) {
        const int add = (t >= d) ? s[t - d] : 0;
        __syncthreads();
        val += add;
        s[t] = val;
        __syncthreads();
    }
    if (t < nb) bsum[t] = val - v;
}

__global__ void scan3(const int* __restrict__ exc, const int* __restrict__ bsum,
                      int* __restrict__ offs, int* __restrict__ cur, int N) {
    const int i = blockIdx.x * blockDim.x + threadIdx.x;
    if (i < N) {
        const int o = exc[i] + bsum[i >> 8];
        offs[i] = o;
        cur[i] = o;
    }
}

// place src ids into dst-CSR order (int atomics on cursors)
__global__ void place(const int* __restrict__ ei, int* __restrict__ cur,
                      int* __restrict__ srcs, int E) {
    int i = blockIdx.x * blockDim.x + threadIdx.x;
    const int stride = gridDim.x * blockDim.x;
    for (int e = i; e < E; e += stride) {
        const int d = ei[E + e];
        const int pos = atomicAdd(&cur[d], 1);
        srcs[pos] = ei[e];
    }
}

// atomic-free segment sum: one wave per dst node; lane l owns cols 2l,2l+1.
// Gathers h_bf16 rows (256B coalesced), accumulates fp32, writes out once.
__global__ __launch_bounds__(256) void segsum(
    const unsigned short* __restrict__ h, const int* __restrict__ offs,
    const int* __restrict__ cnts, const int* __restrict__ srcs,
    float* __restrict__ out, int N)
{
    const int wv = threadIdx.x >> 6;
    const int l  = threadIdx.x & 63;
    const int n  = blockIdx.x * 4 + wv;
    if (n >= N) return;
    const int start = offs[n];
    const int cnt   = cnts[n];
    float ax = 0.f, ay = 0.f;
    for (int c0 = 0; c0 < cnt; c0 += 64) {
        const int rem = cnt - c0;
        const int sv = (l < rem) ? srcs[start + c0 + l] : 0;
        const int m = rem < 64 ? rem : 64;
        for (int j = 0; j < m; ++j) {
            const int s = __shfl(sv, j);
            const unsigned u = *reinterpret_cast<const unsigned*>(h + (size_t)s * DIM + 2 * l);
            union { unsigned u; float f; } lo, hi;
            lo.u = u << 16;
            hi.u = u & 0xffff0000u;
            ax += lo.f;
            ay += hi.f;
        }
    }
    float2* op = reinterpret_cast<float2*>(out + (size_t)n * DIM);
    op[l] = make_float2(ax, ay);
}

extern "C" void kernel_launch(void* const* d_in, const int* in_sizes, int n_in,
                              void* d_out, int out_size, void* d_ws, size_t ws_size,
                              hipStream_t stream) {
    const float* x  = (const float*)d_in[0];
    const float* W  = (const float*)d_in[1];
    const int*   ei = (const int*)d_in[2];
    float* out = (float*)d_out;

    const int N = in_sizes[0] / DIM;   // 100000
    const int E = in_sizes[2] / 2;     // 1600000

    // workspace carve (~33.6 MB; 51.2 MB known available)
    char* w = (char*)d_ws;
    unsigned short* h = (unsigned short*)w; w += (size_t)N * DIM * 2;
    int* cnts = (int*)w; w += (size_t)N * 4;
    int* exc  = (int*)w; w += (size_t)N * 4;
    int* offs = (int*)w; w += (size_t)N * 4;
    int* cur  = (int*)w; w += (size_t)N * 4;
    int* bsum = (int*)w; w += 4096;
    int* srcs = (int*)w; w += (size_t)E * 4;

    const int nb = (N + 255) / 256;    // 391 <= 512

    hipMemsetAsync(cnts, 0, (size_t)N * 4, stream);

    gemm_mfma<<<(N + BM - 1) / BM, 256, 0, stream>>>(x, W, h, N);
    hist <<<2048, 256, 0, stream>>>(ei, cnts, E);
    scan1<<<nb, 256, 0, stream>>>(cnts, exc, bsum, N);
    scan2<<<1, 512, 0, stream>>>(bsum, nb);
    scan3<<<nb, 256, 0, stream>>>(exc, bsum, offs, cur, N);
    place<<<2048, 256, 0, stream>>>(ei, cur, srcs, E);
    segsum<<<(N + 3) / 4, 256, 0, stream>>>(h, offs, cnts, srcs, out, N);
    // no d_out memset needed: segsum writes every row exactly once
}